// Round 4
// baseline (251.044 us; speedup 1.0000x reference)
//
#include <hip/hip_runtime.h>
#include <hip/hip_bf16.h>

typedef __hip_bfloat16 bf16;
// match the builtin's own return type (__fp16 ext_vector(2)) exactly
using hf2 = decltype(__builtin_amdgcn_cvt_pkrtz(0.f, 0.f));
typedef float f32x2 __attribute__((ext_vector_type(2)));

// ---------------------------------------------------------------------------
// Problem constants
// ---------------------------------------------------------------------------
#define BB   2
#define FF   16
#define HH   64
#define WW   64
#define CC   16     // in/out channels == MID
#define NIMG (BB*FF)        // 32
#define PIX  (HH*WW)        // 4096
#define IMGSZ (PIX*CC)      // 65536 elements per image (channel-last)

// scale(=1/sqrt(2)) * log2(e): folded into staged Wq; softmax uses raw v_exp_f32
#define QSCALE_LOG2E 1.0201394f

// ---- packed f16x2 helpers (v_cvt_pkrtz_f16_f32 / v_dot2_f32_f16) ----
__device__ __forceinline__ unsigned pkh2(float a, float b) {
    union { hf2 h; unsigned u; } x;
    x.h = __builtin_amdgcn_cvt_pkrtz(a, b);
    return x.u;
}
__device__ __forceinline__ float fdot2u(unsigned a, unsigned b, float c) {
    union { unsigned u; hf2 h; } A, B;
    A.u = a; B.u = b;
    return __builtin_amdgcn_fdot2(A.h, B.h, c, false);
}
__device__ __forceinline__ f32x2 f2(float a, float b) {
    f32x2 r; r.x = a; r.y = b; return r;
}

// ---- 16-element bf16 I/O (intermediates A/R) ----
__device__ __forceinline__ void ld16bf(const bf16* p, float* x) {
    const uint4* p4 = reinterpret_cast<const uint4*>(p);
    uint4 u0 = p4[0], u1 = p4[1];
    unsigned uu[8] = {u0.x, u0.y, u0.z, u0.w, u1.x, u1.y, u1.z, u1.w};
    #pragma unroll
    for (int k = 0; k < 8; ++k) {
        union { unsigned u; float f; } lo, hi;
        lo.u = uu[k] << 16;
        hi.u = uu[k] & 0xffff0000u;
        x[2 * k] = lo.f;
        x[2 * k + 1] = hi.f;
    }
}

// ---- 16-element fp32 I/O (global inputs/outputs) ----
__device__ __forceinline__ void ld16f(const float* p, float* x) {
    const float4* p4 = reinterpret_cast<const float4*>(p);
    #pragma unroll
    for (int q = 0; q < 4; ++q) {
        float4 v = p4[q];
        x[4 * q] = v.x; x[4 * q + 1] = v.y; x[4 * q + 2] = v.z; x[4 * q + 3] = v.w;
    }
}
__device__ __forceinline__ void st16f(float* p, const float* x) {
    float4* p4 = reinterpret_cast<float4*>(p);
    #pragma unroll
    for (int q = 0; q < 4; ++q)
        p4[q] = make_float4(x[4 * q], x[4 * q + 1], x[4 * q + 2], x[4 * q + 3]);
}

__device__ __forceinline__ unsigned packbf2(float a, float b) {
    union { bf16 h[2]; unsigned u; } pk;
    pk.h[0] = __float2bfloat16(a);
    pk.h[1] = __float2bfloat16(b);
    return pk.u;
}

// ---------------------------------------------------------------------------
// Fused kernel: conv stem (A-row + R-row, + emb-MLP) + stage-X attention.
// One block per sequence (b,f,h): computes conv for its own 64 A-pixels and
// 64 R-pixels from the 3-row input stencil, writes the R row to global
// (consumed by stages Y/T), and feeds the conv output straight into
// posembed+LayerNorm+QKV without a global round-trip.  resx -> A in place.
//
// Phase-1 pairing: 2 threads/token, each owns 8 channels (half = t&1).
// LN stats via shfl_xor(.,1); partner's normalized channels exchanged as
// 4 f16x2-packed words (4 shuffles) straight into the fdot2 projection.
// ---------------------------------------------------------------------------
__global__ __launch_bounds__(256, 4) void convattn_x_kernel(
    const float* __restrict__ hid, const float* __restrict__ ref,
    const float* __restrict__ cw, const float* __restrict__ cb,
    const float* __restrict__ emb,
    const float* __restrict__ e1w, const float* __restrict__ e1b,
    const float* __restrict__ e2w, const float* __restrict__ e2b,
    bf16* __restrict__ A, bf16* __restrict__ R,
    const float* __restrict__ wq, const float* __restrict__ wk,
    const float* __restrict__ wv, const float* __restrict__ wo,
    const float* __restrict__ bo, const float* __restrict__ gw,
    const float* __restrict__ bw)
{
    constexpr int S = 128, HS = 64, KQ = 64;
    constexpr int QB = 4, QP = 2;          // queries / query-pairs per thread
    constexpr int KROW = 10;               // k/v/q token row stride (uints)
    constexpr int QROW = 20;               // o row stride (floats)

    __shared__ unsigned w2l[9 * 128];      // conv weights [tap][oc][ic/2] f16x2
    __shared__ float wolT[256];
    __shared__ unsigned wq2L[128], wk2L[128], wv2L[128];
    __shared__ float bol[16], gl[16], blw[16], cbL[16], hl[16], el[16];
    __shared__ __align__(16) unsigned kU[S * KROW];   // k f16x2; emb partials / o overlay
    __shared__ __align__(16) unsigned vU[S * KROW];   // v bf16x2
    __shared__ __align__(16) unsigned qL[HS * KROW];  // q f16x2 (scaled)

    int t = threadIdx.x;
    int seq = blockIdx.x;                  // (b*FF+f)*HH + h
    int h   = seq & 63;
    int img = seq >> 6;
    int b   = seq >> 10;
    int base = img * IMGSZ + h * (WW * CC);

    // ---- staging ----
    wolT[(t & 15) * 16 + (t >> 4)] = wo[t];
    if (t < 128) {
        float2 qw = reinterpret_cast<const float2*>(wq)[t];
        float2 kw = reinterpret_cast<const float2*>(wk)[t];
        float2 vw = reinterpret_cast<const float2*>(wv)[t];
        wq2L[t] = pkh2(qw.x * QSCALE_LOG2E, qw.y * QSCALE_LOG2E);
        wk2L[t] = pkh2(kw.x, kw.y);
        wv2L[t] = pkh2(vw.x, vw.y);
        int oc = t & 15, c2 = t >> 4;
        #pragma unroll
        for (int k = 0; k < 9; ++k)
            w2l[k * 128 + oc * 8 + c2] =
                pkh2(cw[(oc * 16 + 2 * c2) * 9 + k],
                     cw[(oc * 16 + 2 * c2 + 1) * 9 + k]);
    }
    if (t < 16) { bol[t] = bo[t]; gl[t] = gw[t]; blw[t] = bw[t]; cbL[t] = cb[t]; }

    // ---- phase 0: emb MLP (per block; parallel 256-wide, prt overlays kU) --
    float* prt = reinterpret_cast<float*>(kU);
    {
        int o = t >> 4, seg = t & 15;
        const float* er = emb + b * 512 + seg * 32;
        const float* wr = e1w + o * 512 + seg * 32;
        float p = 0.f;
        #pragma unroll
        for (int k = 0; k < 32; ++k) p = fmaf(er[k], wr[k], p);
        prt[t] = p;
    }
    __syncthreads();
    if (t < 16) {
        float acc = e1b[t];
        #pragma unroll
        for (int s = 0; s < 16; ++s) acc += prt[t * 16 + s];
        hl[t] = acc / (1.f + __expf(-acc));   // silu
    }
    __syncthreads();
    if (t < 16) {
        float acc = e2b[t];
        #pragma unroll
        for (int k = 0; k < 16; ++k) acc = fmaf(hl[k], e2w[t * 16 + k], acc);
        el[t] = acc;
    }
    __syncthreads();

    // ---- phase 1: conv (8 oc) + R write + posembed + LN + QKV -> LDS ----
    {
        int i    = t >> 1;        // token 0..127
        int half = t & 1;
        int db   = half * 8;      // my channel block
        bool isR = (i >= HS);
        int wi   = isR ? (i - HS) : i;
        const float* src = (isR ? ref : hid) + (size_t)img * IMGSZ;

        float x[8];
        #pragma unroll
        for (int k = 0; k < 8; ++k)
            x[k] = cbL[db + k] + (isR ? el[db + k] : 0.f);

        for (int ky = 0; ky < 3; ++ky) {
            int y = h + ky - 1;
            if ((unsigned)y >= 64u) continue;
            for (int kx = 0; kx < 3; ++kx) {
                int xx = wi + kx - 1;
                if ((unsigned)xx >= 64u) continue;
                float xv[16];
                ld16f(src + (((y << 6) + xx) << 4), xv);
                unsigned xpc[8];
                #pragma unroll
                for (int c2 = 0; c2 < 8; ++c2)
                    xpc[c2] = pkh2(xv[2 * c2], xv[2 * c2 + 1]);
                const unsigned* wt = &w2l[(ky * 3 + kx) * 128];
                #pragma unroll
                for (int oo = 0; oo < 8; ++oo) {
                    float a = x[oo];
                    #pragma unroll
                    for (int c2 = 0; c2 < 8; ++c2)
                        a = fdot2u(xpc[c2], wt[(db + oo) * 8 + c2], a);
                    x[oo] = a;
                }
            }
        }

        if (isR) {   // persist R row for stages Y/T (bf16, 16B per thread)
            union { unsigned u[4]; uint4 v; } rw;
            #pragma unroll
            for (int e = 0; e < 4; ++e)
                rw.u[e] = packbf2(x[2 * e], x[2 * e + 1]);
            *reinterpret_cast<uint4*>(R + base + wi * CC + db) = rw.v;
        }

        // posembed: ch k<8 += sin(fi*om[k]); ch k>=8 += cos(fi*om[k-8])
        const float om[8] = {1.f, 0.31622776601683794f, 0.1f, 0.031622776601683794f,
                             0.01f, 0.0031622776601683794f, 0.001f, 0.00031622776601683794f};
        float fi = (float)i;
        #pragma unroll
        for (int k = 0; k < 8; ++k) {
            float sv, cv;
            __sincosf(fi * om[k], &sv, &cv);
            x[k] += half ? cv : sv;
        }

        // LayerNorm across the thread pair
        float s8 = 0.f;
        #pragma unroll
        for (int k = 0; k < 8; ++k) s8 += x[k];
        float m = (s8 + __shfl_xor(s8, 1)) * (1.f / 16.f);
        float v8 = 0.f;
        #pragma unroll
        for (int k = 0; k < 8; ++k) { float d = x[k] - m; v8 = fmaf(d, d, v8); }
        float var = (v8 + __shfl_xor(v8, 1)) * (1.f / 16.f);
        float rs = rsqrtf(var + 1e-5f);

        unsigned xpm[4];
        #pragma unroll
        for (int e = 0; e < 4; ++e) {
            float a0 = (x[2 * e]     - m) * rs * gl[db + 2 * e]     + blw[db + 2 * e];
            float a1 = (x[2 * e + 1] - m) * rs * gl[db + 2 * e + 1] + blw[db + 2 * e + 1];
            xpm[e] = pkh2(a0, a1);
        }
        unsigned xp[8];
        #pragma unroll
        for (int e = 0; e < 4; ++e) {
            unsigned oth = __shfl_xor(xpm[e], 1);
            xp[e]     = half ? oth    : xpm[e];
            xp[e + 4] = half ? xpm[e] : oth;
        }

        // QKV projections (8 dims each) via fdot2
        float qv[8], kv[8], vv[8];
        #pragma unroll
        for (int dd = 0; dd < 8; ++dd) {
            int d = db + dd;
            float aq = 0.f, ak = 0.f, av = 0.f;
            #pragma unroll
            for (int c2 = 0; c2 < 8; ++c2) {
                aq = fdot2u(xp[c2], wq2L[d * 8 + c2], aq);
                ak = fdot2u(xp[c2], wk2L[d * 8 + c2], ak);
                av = fdot2u(xp[c2], wv2L[d * 8 + c2], av);
            }
            qv[dd] = aq; kv[dd] = ak; vv[dd] = av;
        }
        int row = i * KROW + (db >> 1);
        uint2* kr = reinterpret_cast<uint2*>(&kU[row]);
        uint2* vr = reinterpret_cast<uint2*>(&vU[row]);
        #pragma unroll
        for (int e = 0; e < 2; ++e) {
            kr[e] = make_uint2(pkh2(kv[4 * e], kv[4 * e + 1]),
                               pkh2(kv[4 * e + 2], kv[4 * e + 3]));
            vr[e] = make_uint2(packbf2(vv[4 * e], vv[4 * e + 1]),
                               packbf2(vv[4 * e + 2], vv[4 * e + 3]));
        }
        if (i < HS) {
            uint2* qr = reinterpret_cast<uint2*>(&qL[i * KROW + (db >> 1)]);
            #pragma unroll
            for (int e = 0; e < 2; ++e)
                qr[e] = make_uint2(pkh2(qv[4 * e], qv[4 * e + 1]),
                                   pkh2(qv[4 * e + 2], qv[4 * e + 3]));
        }
    }
    __syncthreads();

    // ---- phase 2: single-pass softmax (exp2 domain), parity key split ----
    int qg  = t >> 4;          // query group
    int hd  = (t >> 1) & 7;    // head
    int half = t & 1;          // key parity
    float* oL = reinterpret_cast<float*>(kU);   // overlay after barrier
    {
        unsigned q2[QB];
        f32x2 l2[QP], a0p[QP], a1p[QP];
        #pragma unroll
        for (int qq = 0; qq < QB; ++qq)
            q2[qq] = qL[(qg * QB + qq) * KROW + hd];
        #pragma unroll
        for (int m = 0; m < QP; ++m) {
            l2[m] = f2(0.f, 0.f); a0p[m] = f2(0.f, 0.f); a1p[m] = f2(0.f, 0.f);
        }
        const unsigned* kp = &kU[half * KROW + hd];
        const unsigned* vp = &vU[half * KROW + hd];
        #pragma unroll 8
        for (int jj = 0; jj < KQ; ++jj) {            // key j = 2*jj + half
            unsigned ku = kp[jj * 2 * KROW];
            unsigned vu = vp[jj * 2 * KROW];
            union { unsigned u; float f; } v0, v1;
            v0.u = vu << 16; v1.u = vu & 0xffff0000u;
            f32x2 v00 = f2(v0.f, v0.f);
            f32x2 v11 = f2(v1.f, v1.f);
            #pragma unroll
            for (int m = 0; m < QP; ++m) {
                f32x2 p2;
                p2.x = __builtin_amdgcn_exp2f(fdot2u(q2[2 * m], ku, 0.f));
                p2.y = __builtin_amdgcn_exp2f(fdot2u(q2[2 * m + 1], ku, 0.f));
                l2[m] += p2;                                    // v_pk_add_f32
                a0p[m] = __builtin_elementwise_fma(p2, v00, a0p[m]);  // v_pk_fma_f32
                a1p[m] = __builtin_elementwise_fma(p2, v11, a1p[m]);
            }
        }
        #pragma unroll
        for (int m = 0; m < QP; ++m) {
            l2[m].x  += __shfl_xor(l2[m].x, 1);  l2[m].y  += __shfl_xor(l2[m].y, 1);
            a0p[m].x += __shfl_xor(a0p[m].x, 1); a0p[m].y += __shfl_xor(a0p[m].y, 1);
            a1p[m].x += __shfl_xor(a1p[m].x, 1); a1p[m].y += __shfl_xor(a1p[m].y, 1);
        }
        __syncthreads();   // all k/q reads done; kU reusable as oL
        if (half == 0) {
            #pragma unroll
            for (int m = 0; m < QP; ++m) {
                float inv0 = 1.f / l2[m].x;
                float inv1 = 1.f / l2[m].y;
                *reinterpret_cast<float2*>(
                    &oL[(qg * QB + 2 * m) * QROW + 2 * hd]) =
                    make_float2(a0p[m].x * inv0, a1p[m].x * inv0);
                *reinterpret_cast<float2*>(
                    &oL[(qg * QB + 2 * m + 1) * QROW + 2 * hd]) =
                    make_float2(a0p[m].y * inv1, a1p[m].y * inv1);
            }
        }
    }
    __syncthreads();

    // ---- phase 3: out-proj, in-place bf16x2 write into A ----
    #pragma unroll
    for (int rep = 0; rep < 2; ++rep) {
        int idx = t + rep * 256;          // < HS*8
        int cp  = idx & 7;                // channel pair
        int tok = idx >> 3;
        const float* orow = &oL[tok * QROW];
        float acc0 = bol[2 * cp], acc1 = bol[2 * cp + 1];
        #pragma unroll
        for (int d = 0; d < 16; ++d) {
            acc0 = fmaf(orow[d], wolT[d * 16 + 2 * cp], acc0);
            acc1 = fmaf(orow[d], wolT[d * 16 + 2 * cp + 1], acc1);
        }
        *reinterpret_cast<unsigned*>(A + base + tok * CC + 2 * cp) =
            packbf2(acc0, acc1);
    }
}

// ---------------------------------------------------------------------------
// Attention stage (Y / T). 256 threads; TPT = 256/(SEQPB*S) threads per token.
// Sequence s: tokens j<S/2 from A, j>=S/2 from R.
//   token j elem offset = (s/d2)*str1 + (s%d2)*str2 + j*tokStride
// Output (first S/2 tokens) written in place into A (bf16); the T stage also
// writes an f16x2 shadow copy (A16) consumed by conv_out with zero unpack.
// ---------------------------------------------------------------------------
template<int S, int SEQPB, int MINW, bool F16OUT>
__global__ __launch_bounds__(256, MINW) void attn_kernel(
    bf16* __restrict__ A, const bf16* __restrict__ R,
    unsigned* __restrict__ A16,
    int d2, int str1, int str2, int tokStride,
    const float* __restrict__ wq, const float* __restrict__ wk,
    const float* __restrict__ wv, const float* __restrict__ wo,
    const float* __restrict__ bo, const float* __restrict__ gw,
    const float* __restrict__ bw)
{
    constexpr int HS  = S / 2;             // queries per sequence
    constexpr int KQ  = S / 2;             // keys per phase-2 thread (parity)
    constexpr int TPT = 256 / (SEQPB * S); // threads per token: 1 or 2
    constexpr int NDIM = 16 / TPT;         // qkv dims per phase-1 thread
    constexpr int ITEMS = 256 / SEQPB;     // phase-2 threads per sequence
    constexpr int NQG = ITEMS / 16;        // query groups per sequence
    constexpr int QB  = HS / NQG;          // queries per phase-2 thread
    constexpr int QP  = QB / 2;            // query PAIRS per phase-2 thread
    constexpr int KROW = 10;               // k/v/q token row stride (uints)
    constexpr int QROW = 20;               // o row stride (floats)
    constexpr int LSQ = (SEQPB == 1) ? 0 : ((SEQPB == 2) ? 1 : 2);
    constexpr int NW3 = SEQPB * HS * 8 / 256;  // phase-3 reps

    __shared__ float wolT[256];
    __shared__ unsigned wq2L[128], wk2L[128], wv2L[128];   // f16x2-packed rows
    __shared__ float bol[16], gl[16], blw[16];
    __shared__ __align__(16) unsigned kU[SEQPB * S * KROW];   // k f16x2; o overlay after barrier
    __shared__ __align__(16) unsigned vU[SEQPB * S * KROW];   // v bf16x2
    __shared__ __align__(16) unsigned qL[SEQPB * HS * KROW];  // q f16x2 (scaled)
    __shared__ int bases[SEQPB];

    int t = threadIdx.x;
    wolT[(t & 15) * 16 + (t >> 4)] = wo[t];   // transposed: [d][c]
    if (t < 128) {
        float2 qw = reinterpret_cast<const float2*>(wq)[t];
        float2 kw = reinterpret_cast<const float2*>(wk)[t];
        float2 vw = reinterpret_cast<const float2*>(wv)[t];
        wq2L[t] = pkh2(qw.x * QSCALE_LOG2E, qw.y * QSCALE_LOG2E);
        wk2L[t] = pkh2(kw.x, kw.y);
        wv2L[t] = pkh2(vw.x, vw.y);
    }
    if (t < 16) { bol[t] = bo[t]; gl[t] = gw[t]; blw[t] = bw[t]; }
    if (t < SEQPB) {
        int seq = blockIdx.x * SEQPB + t;
        bases[t] = (seq / d2) * str1 + (seq % d2) * str2;
    }
    __syncthreads();

    // ---- phase 1: token load, +posembed, LayerNorm, QKV (fdot2) -> LDS ----
    {
        int tokIdx = (TPT == 2) ? (t >> 1) : t;
        int db     = (TPT == 2) ? ((t & 1) * 8) : 0;
        int sq = tokIdx & (SEQPB - 1);     // sq fastest: adjacent lanes coalesce
        int i  = tokIdx >> LSQ;
        const bf16* src = (i < HS)
            ? (A + bases[sq] + (size_t)i * tokStride)
            : (R + bases[sq] + (size_t)(i - HS) * tokStride);
        float x[16];
        ld16bf(src, x);
        const float om[8] = {1.f, 0.31622776601683794f, 0.1f, 0.031622776601683794f,
                             0.01f, 0.0031622776601683794f, 0.001f, 0.00031622776601683794f};
        float fi = (float)i;
        #pragma unroll
        for (int k = 0; k < 8; ++k) {
            float sv, cv;
            __sincosf(fi * om[k], &sv, &cv);
            x[k]     += sv;
            x[k + 8] += cv;
        }
        float m = 0.f;
        #pragma unroll
        for (int c = 0; c < 16; ++c) m += x[c];
        m *= (1.f / 16.f);
        float var = 0.f;
        #pragma unroll
        for (int c = 0; c < 16; ++c) { float d = x[c] - m; var = fmaf(d, d, var); }
        var *= (1.f / 16.f);
        float rs = rsqrtf(var + 1e-5f);
        float xn[16];
        #pragma unroll
        for (int c = 0; c < 16; ++c) xn[c] = (x[c] - m) * rs * gl[c] + blw[c];

        unsigned xp[8];
        #pragma unroll
        for (int c2 = 0; c2 < 8; ++c2) xp[c2] = pkh2(xn[2 * c2], xn[2 * c2 + 1]);

        float qv[NDIM], kv[NDIM], vv[NDIM];
        #pragma unroll
        for (int dd = 0; dd < NDIM; ++dd) {
            int d = db + dd;
            float aq = 0.f, ak = 0.f, av = 0.f;
            #pragma unroll
            for (int c2 = 0; c2 < 8; ++c2) {
                aq = fdot2u(xp[c2], wq2L[d * 8 + c2], aq);
                ak = fdot2u(xp[c2], wk2L[d * 8 + c2], ak);
                av = fdot2u(xp[c2], wv2L[d * 8 + c2], av);
            }
            qv[dd] = aq; kv[dd] = ak; vv[dd] = av;
        }
        int row = (sq * S + i) * KROW + (db >> 1);   // uint index, even
        uint2* kr = reinterpret_cast<uint2*>(&kU[row]);
        uint2* vr = reinterpret_cast<uint2*>(&vU[row]);
        #pragma unroll
        for (int e = 0; e < NDIM / 4; ++e) {
            kr[e] = make_uint2(pkh2(kv[4 * e], kv[4 * e + 1]),
                               pkh2(kv[4 * e + 2], kv[4 * e + 3]));
            vr[e] = make_uint2(packbf2(vv[4 * e], vv[4 * e + 1]),
                               packbf2(vv[4 * e + 2], vv[4 * e + 3]));
        }
        if (i < HS) {
            uint2* qr = reinterpret_cast<uint2*>(&qL[(sq * HS + i) * KROW + (db >> 1)]);
            #pragma unroll
            for (int e = 0; e < NDIM / 4; ++e)
                qr[e] = make_uint2(pkh2(qv[4 * e], qv[4 * e + 1]),
                                   pkh2(qv[4 * e + 2], qv[4 * e + 3]));
        }
    }
    __syncthreads();

    // ---- phase 2: single-pass softmax (exp2 domain), parity key split,
    //      query-paired packed-FP32 accumulation ----
    int sq2 = t / ITEMS;
    int r   = t % ITEMS;
    int qg  = r >> 4;          // query group (QB queries)
    int hd  = (r >> 1) & 7;    // head
    int half = r & 1;          // key parity
    float* oL = reinterpret_cast<float*>(kU);   // overlay after barrier
    {
        unsigned q2[QB];
        f32x2 l2[QP], a0p[QP], a1p[QP];
        #pragma unroll
        for (int qq = 0; qq < QB; ++qq)
            q2[qq] = qL[(sq2 * HS + qg * QB + qq) * KROW + hd];  // scaled f16x2
        #pragma unroll
        for (int m = 0; m < QP; ++m) {
            l2[m] = f2(0.f, 0.f); a0p[m] = f2(0.f, 0.f); a1p[m] = f2(0.f, 0.f);
        }
        const unsigned* kp = &kU[(sq2 * S + half) * KROW + hd];
        const unsigned* vp = &vU[(sq2 * S + half) * KROW + hd];
        #pragma unroll 8
        for (int jj = 0; jj < KQ; ++jj) {            // key j = 2*jj + half
            unsigned ku = kp[jj * 2 * KROW];
            unsigned vu = vp[jj * 2 * KROW];
            union { unsigned u; float f; } v0, v1;
            v0.u = vu << 16; v1.u = vu & 0xffff0000u;
            f32x2 v00 = f2(v0.f, v0.f);
            f32x2 v11 = f2(v1.f, v1.f);
            #pragma unroll
            for (int m = 0; m < QP; ++m) {
                f32x2 p2;
                p2.x = __builtin_amdgcn_exp2f(fdot2u(q2[2 * m], ku, 0.f));
                p2.y = __builtin_amdgcn_exp2f(fdot2u(q2[2 * m + 1], ku, 0.f));
                l2[m] += p2;                                    // v_pk_add_f32
                a0p[m] = __builtin_elementwise_fma(p2, v00, a0p[m]);  // v_pk_fma_f32
                a1p[m] = __builtin_elementwise_fma(p2, v11, a1p[m]);
            }
        }
        #pragma unroll
        for (int m = 0; m < QP; ++m) {
            l2[m].x  += __shfl_xor(l2[m].x, 1);  l2[m].y  += __shfl_xor(l2[m].y, 1);
            a0p[m].x += __shfl_xor(a0p[m].x, 1); a0p[m].y += __shfl_xor(a0p[m].y, 1);
            a1p[m].x += __shfl_xor(a1p[m].x, 1); a1p[m].y += __shfl_xor(a1p[m].y, 1);
        }
        __syncthreads();   // all k/q reads done in every thread; kU reusable as oL
        if (half == 0) {
            #pragma unroll
            for (int m = 0; m < QP; ++m) {
                float inv0 = 1.f / l2[m].x;
                float inv1 = 1.f / l2[m].y;
                *reinterpret_cast<float2*>(
                    &oL[(sq2 * HS + qg * QB + 2 * m) * QROW + 2 * hd]) =
                    make_float2(a0p[m].x * inv0, a1p[m].x * inv0);
                *reinterpret_cast<float2*>(
                    &oL[(sq2 * HS + qg * QB + 2 * m + 1) * QROW + 2 * hd]) =
                    make_float2(a0p[m].y * inv1, a1p[m].y * inv1);
            }
        }
    }
    __syncthreads();

    // ---- phase 3: out-proj, in-place bf16x2 write; sq fastest for lines ----
    #pragma unroll
    for (int rep = 0; rep < NW3; ++rep) {
        int idx = t + rep * 256;          // < SEQPB*HS*8
        int cp  = idx & 7;                // channel pair
        int g   = idx >> 3;
        int sq3 = g & (SEQPB - 1);
        int tok = g >> LSQ;
        const float* orow = &oL[(sq3 * HS + tok) * QROW];
        float acc0 = bol[2 * cp], acc1 = bol[2 * cp + 1];
        #pragma unroll
        for (int d = 0; d < 16; ++d) {
            acc0 = fmaf(orow[d], wolT[d * 16 + 2 * cp], acc0);
            acc1 = fmaf(orow[d], wolT[d * 16 + 2 * cp + 1], acc1);
        }
        int off = bases[sq3] + tok * tokStride;
        *reinterpret_cast<unsigned*>(A + off + 2 * cp) = packbf2(acc0, acc1);
        if constexpr (F16OUT)
            A16[(off >> 1) + cp] = pkh2(acc0, acc1);   // f16 shadow for conv_out
    }
}

// ---------------------------------------------------------------------------
// Kernel 5: out = hidden + conv(rest).  Input is the f16x2 shadow written by
// the T attention stage: operands feed fdot2 directly, zero unpack.
// ---------------------------------------------------------------------------
__global__ __launch_bounds__(256) void conv_out_kernel(
    const unsigned* __restrict__ A16, const float* __restrict__ hid,
    const float* __restrict__ pw, const float* __restrict__ pb,
    float* __restrict__ out)
{
    __shared__ unsigned w2l[9 * 128];   // [tap][oc][ic/2] f16x2
    __shared__ float bl[16];
    int t = threadIdx.x;
    if (t < 128) {
        int oc = t & 15, c2 = t >> 4;
        #pragma unroll
        for (int k = 0; k < 9; ++k)
            w2l[k * 128 + oc * 8 + c2] =
                pkh2(pw[(oc * 16 + 2 * c2) * 9 + k],
                     pw[(oc * 16 + 2 * c2 + 1) * 9 + k]);
    }
    if (t < 16) bl[t] = pb[t];
    __syncthreads();

    int gid = blockIdx.x * 256 + t;   // 0 .. NIMG*PIX-1
    int wi = gid & 63, hi = (gid >> 6) & 63;
    int img = gid >> 12;
    const unsigned* inp = A16 + ((size_t)img << 15);   // 32768 uints / image
    float acc[16];
    #pragma unroll
    for (int oc = 0; oc < 16; ++oc) acc[oc] = bl[oc];

    for (int ky = 0; ky < 3; ++ky) {
        int y = hi + ky - 1;
        if ((unsigned)y >= 64u) continue;
        for (int kx = 0; kx < 3; ++kx) {
            int x = wi + kx - 1;
            if ((unsigned)x >= 64u) continue;
            const uint4* p4 = reinterpret_cast<const uint4*>(
                inp + (((y << 6) + x) << 3));           // 8 uints / pixel
            uint4 u0 = p4[0], u1 = p4[1];
            unsigned xp[8] = {u0.x, u0.y, u0.z, u0.w, u1.x, u1.y, u1.z, u1.w};
            const unsigned* wt = &w2l[(ky * 3 + kx) * 128];
            #pragma unroll
            for (int oc = 0; oc < 16; ++oc) {
                float a = acc[oc];
                #pragma unroll
                for (int c2 = 0; c2 < 8; ++c2)
                    a = fdot2u(xp[c2], wt[oc * 8 + c2], a);
                acc[oc] = a;
            }
        }
    }
    size_t off = ((size_t)gid) << 4;
    float hv[16];
    ld16f(hid + off, hv);
    float res[16];
    #pragma unroll
    for (int k = 0; k < 16; ++k) res[k] = acc[k] + hv[k];
    st16f(out + off, res);
}

// ---------------------------------------------------------------------------
extern "C" void kernel_launch(void* const* d_in, const int* in_sizes, int n_in,
                              void* d_out, int out_size, void* d_ws, size_t ws_size,
                              hipStream_t stream) {
    const float* hid  = (const float*)d_in[0];
    const float* ref  = (const float*)d_in[1];
    const float* emb  = (const float*)d_in[2];
    const float* ciw  = (const float*)d_in[3];
    const float* cib  = (const float*)d_in[4];
    const float* e1w  = (const float*)d_in[5];
    const float* e1b  = (const float*)d_in[6];
    const float* e2w  = (const float*)d_in[7];
    const float* e2b  = (const float*)d_in[8];
    const float* wqx  = (const float*)d_in[9];
    const float* wkx  = (const float*)d_in[10];
    const float* wvx  = (const float*)d_in[11];
    const float* wox  = (const float*)d_in[12];
    const float* box_ = (const float*)d_in[13];
    const float* wqy  = (const float*)d_in[14];
    const float* wky  = (const float*)d_in[15];
    const float* wvy  = (const float*)d_in[16];
    const float* woy  = (const float*)d_in[17];
    const float* boy  = (const float*)d_in[18];
    const float* wqt  = (const float*)d_in[19];
    const float* wkt  = (const float*)d_in[20];
    const float* wvt  = (const float*)d_in[21];
    const float* wot  = (const float*)d_in[22];
    const float* bot  = (const float*)d_in[23];
    const float* ng   = (const float*)d_in[24];
    const float* nb   = (const float*)d_in[25];
    const float* pjw  = (const float*)d_in[26];
    const float* pjb  = (const float*)d_in[27];

    bf16* A = (bf16*)d_ws;     // 4 MiB in workspace
    unsigned* A16 = (unsigned*)((char*)d_ws + (4 << 20));  // 4 MiB f16 shadow
    bf16* R = (bf16*)d_out;    // 4 MiB scratch inside the 8 MiB f32 output buf
                               // (fully overwritten by conv_out at the end)

    // Stage X (fused conv stem): seq=(b,f,h), computes conv rows + attention,
    // writes R (bf16) and resx->A in place.
    convattn_x_kernel<<<BB * FF * HH, 256, 0, stream>>>(
        hid, ref, ciw, cib, emb, e1w, e1b, e2w, e2b,
        A, R, wqx, wkx, wvx, wox, box_, ng, nb);

    // Stage Y: seq=(b,f,w), S=2H=128, tok stride W*C; 2 consecutive w, TPT=1
    attn_kernel<128, 2, 4, false><<<(BB * FF * WW) / 2, 256, 0, stream>>>(
        A, R, nullptr, WW, IMGSZ, CC, WW * CC, wqy, wky, wvy, woy, boy, ng, nb);
    // Stage T: seq=(b,h,w), S=2F=32, tok stride H*W*C; 4 consecutive w, TPT=2
    // writes bf16 A (unused afterwards) + f16 shadow A16 for conv_out
    attn_kernel<32, 4, 8, true><<<(BB * HH * WW) / 4, 256, 0, stream>>>(
        A, R, A16, HH * WW, FF * IMGSZ, CC, IMGSZ, wqt, wkt, wvt, wot, bot, ng, nb);

    conv_out_kernel<<<(NIMG * PIX) / 256, 256, 0, stream>>>(A16, hid, pjw, pjb, (float*)d_out);
}

// Round 6
// 233.194 us; speedup vs baseline: 1.0765x; 1.0765x over previous
//
#include <hip/hip_runtime.h>
#include <hip/hip_bf16.h>

typedef __hip_bfloat16 bf16;
// match the builtin's own return type (__fp16 ext_vector(2)) exactly
using hf2 = decltype(__builtin_amdgcn_cvt_pkrtz(0.f, 0.f));
typedef float f32x2 __attribute__((ext_vector_type(2)));

// ---------------------------------------------------------------------------
// Problem constants
// ---------------------------------------------------------------------------
#define BB   2
#define FF   16
#define HH   64
#define WW   64
#define CC   16     // in/out channels == MID
#define NIMG (BB*FF)        // 32
#define PIX  (HH*WW)        // 4096
#define IMGSZ (PIX*CC)      // 65536 elements per image (channel-last)

// scale(=1/sqrt(2)) * log2(e): folded into staged Wq; softmax uses raw v_exp_f32
#define QSCALE_LOG2E 1.0201394f

// ---- packed f16x2 helpers (v_cvt_pkrtz_f16_f32 / v_dot2_f32_f16) ----
__device__ __forceinline__ unsigned pkh2(float a, float b) {
    union { hf2 h; unsigned u; } x;
    x.h = __builtin_amdgcn_cvt_pkrtz(a, b);
    return x.u;
}
__device__ __forceinline__ float fdot2u(unsigned a, unsigned b, float c) {
    union { unsigned u; hf2 h; } A, B;
    A.u = a; B.u = b;
    return __builtin_amdgcn_fdot2(A.h, B.h, c, false);
}
__device__ __forceinline__ f32x2 f2(float a, float b) {
    f32x2 r; r.x = a; r.y = b; return r;
}

// ---- 16-element bf16 I/O ----
__device__ __forceinline__ void ld16bf(const bf16* p, float* x) {
    const uint4* p4 = reinterpret_cast<const uint4*>(p);
    uint4 u0 = p4[0], u1 = p4[1];
    unsigned uu[8] = {u0.x, u0.y, u0.z, u0.w, u1.x, u1.y, u1.z, u1.w};
    #pragma unroll
    for (int k = 0; k < 8; ++k) {
        union { unsigned u; float f; } lo, hi;
        lo.u = uu[k] << 16;
        hi.u = uu[k] & 0xffff0000u;
        x[2 * k] = lo.f;
        x[2 * k + 1] = hi.f;
    }
}
__device__ __forceinline__ void st16bf(bf16* p, const float* x) {
    union { bf16 h[16]; uint4 u[2]; } o;
    #pragma unroll
    for (int k = 0; k < 16; ++k) o.h[k] = __float2bfloat16(x[k]);
    uint4* p4 = reinterpret_cast<uint4*>(p);
    p4[0] = o.u[0];
    p4[1] = o.u[1];
}

// ---- 16-element fp32 I/O ----
__device__ __forceinline__ void ld16f(const float* p, float* x) {
    const float4* p4 = reinterpret_cast<const float4*>(p);
    #pragma unroll
    for (int q = 0; q < 4; ++q) {
        float4 v = p4[q];
        x[4 * q] = v.x; x[4 * q + 1] = v.y; x[4 * q + 2] = v.z; x[4 * q + 3] = v.w;
    }
}
__device__ __forceinline__ void st16f(float* p, const float* x) {
    float4* p4 = reinterpret_cast<float4*>(p);
    #pragma unroll
    for (int q = 0; q < 4; ++q)
        p4[q] = make_float4(x[4 * q], x[4 * q + 1], x[4 * q + 2], x[4 * q + 3]);
}

__device__ __forceinline__ unsigned packbf2(float a, float b) {
    union { bf16 h[2]; unsigned u; } pk;
    pk.h[0] = __float2bfloat16(a);
    pk.h[1] = __float2bfloat16(b);
    return pk.u;
}

// ---------------------------------------------------------------------------
// Kernel 1: conv stem on hidden (->A) and ref (->R, + fused emb-MLP).
// v0.53: block (4 rows of one image-half) stages its 6 stencil rows ONCE,
// pre-packed f16x2, into LDS (px stride 10 uints; b64 reads <=2-way/phase).
// Conv reads 4 x ds_read_b64 per tap instead of 4 global float4 + 8 packs.
// emb-MLP parallelized 256-wide (partials + LDS reduce).
// ---------------------------------------------------------------------------
__global__ __launch_bounds__(256) void conv_in_kernel(
    const float* __restrict__ hid, const float* __restrict__ ref,
    const float* __restrict__ cw, const float* __restrict__ cb,
    const float* __restrict__ emb,
    const float* __restrict__ e1w, const float* __restrict__ e1b,
    const float* __restrict__ e2w, const float* __restrict__ e2b,
    bf16* __restrict__ A, bf16* __restrict__ R)
{
    __shared__ unsigned w2l[9 * 128];   // [tap][oc][ic/2] f16x2
    __shared__ float bl[16], hl[16], el[16];
    __shared__ __align__(16) unsigned stg[6 * 64 * 10];   // 15360 B staged rows

    int t = threadIdx.x;
    if (t < 128) {
        int oc = t & 15, c2 = t >> 4;
        #pragma unroll
        for (int k = 0; k < 9; ++k)
            w2l[k * 128 + oc * 8 + c2] =
                pkh2(cw[(oc * 16 + 2 * c2) * 9 + k],
                     cw[(oc * 16 + 2 * c2 + 1) * 9 + k]);
    }
    if (t < 16) bl[t] = cb[t];

    int gid  = blockIdx.x * 256 + t;       // 0 .. 2*NIMG*PIX-1
    int wi   = gid & 63;
    int hi   = (gid >> 6) & 63;
    int r0   = hi & ~3;                    // block-uniform: 4 rows per block
    int img2 = gid >> 12;                  // uniform per block
    int isref = img2 >> 5;
    int img  = img2 & 31;
    int bi   = img >> 4;

    if (isref) {        // block-uniform branch: barriers inside are safe
        float* red = reinterpret_cast<float*>(stg);   // overlay, freed below
        {
            int o = t >> 4, seg = t & 15;
            const float* er = emb + bi * 512 + seg * 32;
            const float* wr = e1w + o * 512 + seg * 32;
            float p = 0.f;
            #pragma unroll
            for (int k = 0; k < 32; ++k) p = fmaf(er[k], wr[k], p);
            red[t] = p;
        }
        __syncthreads();
        if (t < 16) {
            float acc = e1b[t];
            #pragma unroll
            for (int s = 0; s < 16; ++s) acc += red[t * 16 + s];
            hl[t] = acc / (1.f + __expf(-acc));   // silu
        }
        __syncthreads();
        if (t < 16) {
            float acc = e2b[t];
            #pragma unroll
            for (int k = 0; k < 16; ++k) acc = fmaf(hl[k], e2w[t * 16 + k], acc);
            el[t] = acc;
        }
        __syncthreads();   // red region free; el ready (also fenced below)
    }

    // ---- stage 6 rows (r0-1 .. r0+4), packed f16x2, px stride 10 uints ----
    const float* inp = (isref ? ref : hid) + (size_t)img * IMGSZ;
    #pragma unroll
    for (int pass = 0; pass < 2; ++pass) {
        int s = t + pass * 256;
        if (s < 384) {
            int px = s & 63, rr = s >> 6;
            int y  = r0 - 1 + rr;
            if ((unsigned)y < 64u) {
                float xv[16];
                ld16f(inp + (((y << 6) + px) << 4), xv);
                uint2* dst = reinterpret_cast<uint2*>(&stg[(rr * 64 + px) * 10]);
                #pragma unroll
                for (int e = 0; e < 4; ++e)
                    dst[e] = make_uint2(pkh2(xv[4 * e],     xv[4 * e + 1]),
                                        pkh2(xv[4 * e + 2], xv[4 * e + 3]));
            }
        }
    }
    __syncthreads();

    // ---- conv: 1 thread per pixel, 16 oc, operands from LDS ----
    int rb = hi & 3;
    float acc[16];
    #pragma unroll
    for (int oc = 0; oc < 16; ++oc)
        acc[oc] = bl[oc] + (isref ? el[oc] : 0.f);

    #pragma unroll
    for (int ky = 0; ky < 3; ++ky) {
        int y = hi + ky - 1;
        if ((unsigned)y >= 64u) continue;
        int rr = rb + ky;
        #pragma unroll
        for (int kx = 0; kx < 3; ++kx) {
            int xx = wi + kx - 1;
            if ((unsigned)xx >= 64u) continue;
            const uint2* pp = reinterpret_cast<const uint2*>(&stg[(rr * 64 + xx) * 10]);
            uint2 p0 = pp[0], p1 = pp[1], p2 = pp[2], p3 = pp[3];
            unsigned xp[8] = {p0.x, p0.y, p1.x, p1.y, p2.x, p2.y, p3.x, p3.y};
            const unsigned* wt = &w2l[(ky * 3 + kx) * 128];
            #pragma unroll
            for (int oc = 0; oc < 16; ++oc) {
                float a = acc[oc];
                #pragma unroll
                for (int c2 = 0; c2 < 8; ++c2)
                    a = fdot2u(xp[c2], wt[oc * 8 + c2], a);
                acc[oc] = a;
            }
        }
    }
    bf16* op = (isref ? R : A) + ((size_t)(img * PIX + (hi << 6) + wi) << 4);
    st16bf(op, acc);
}

// ---------------------------------------------------------------------------
// Attention stage. 256 threads; TPT = 256/(SEQPB*S) threads per token.
// Sequence s: tokens j<S/2 from A, j>=S/2 from R.
//   token j elem offset = (s/d2)*str1 + (s%d2)*str2 + j*tokStride
// Output (first S/2 tokens) written in place into A (bf16); the T stage also
// writes an f16x2 shadow copy (A16) consumed by conv_out with zero unpack.
//
// TPT==2 phase-1 uses the half-channel split (each pair thread loads only its
// 8 channels, LN stats via shfl_xor(1), packed-word exchange via 4 shuffles).
// Phase 2: query-paired packed-FP32 softmax accumulation (pk_add/pk_fma).
// ---------------------------------------------------------------------------
template<int S, int SEQPB, int MINW, bool F16OUT>
__global__ __launch_bounds__(256, MINW) void attn_kernel(
    bf16* __restrict__ A, const bf16* __restrict__ R,
    unsigned* __restrict__ A16,
    int d2, int str1, int str2, int tokStride,
    const float* __restrict__ wq, const float* __restrict__ wk,
    const float* __restrict__ wv, const float* __restrict__ wo,
    const float* __restrict__ bo, const float* __restrict__ gw,
    const float* __restrict__ bw)
{
    constexpr int HS  = S / 2;             // queries per sequence
    constexpr int KQ  = S / 2;             // keys per phase-2 thread (parity)
    constexpr int TPT = 256 / (SEQPB * S); // threads per token: 1 or 2
    constexpr int ITEMS = 256 / SEQPB;     // phase-2 threads per sequence
    constexpr int NQG = ITEMS / 16;        // query groups per sequence
    constexpr int QB  = HS / NQG;          // queries per phase-2 thread
    constexpr int QP  = QB / 2;            // query PAIRS per phase-2 thread
    constexpr int KROW = 10;               // k/v/q token row stride (uints)
    constexpr int QROW = 20;               // o row stride (floats)
    constexpr int LSQ = (SEQPB == 1) ? 0 : ((SEQPB == 2) ? 1 : 2);
    constexpr int NW3 = SEQPB * HS * 8 / 256;  // phase-3 reps

    __shared__ float wolT[256];
    __shared__ unsigned wq2L[128], wk2L[128], wv2L[128];   // f16x2-packed rows
    __shared__ float bol[16], gl[16], blw[16];
    __shared__ __align__(16) unsigned kU[SEQPB * S * KROW];   // k f16x2; o overlay
    __shared__ __align__(16) unsigned vU[SEQPB * S * KROW];   // v bf16x2
    __shared__ __align__(16) unsigned qL[SEQPB * HS * KROW];  // q f16x2 (scaled)
    __shared__ int bases[SEQPB];

    int t = threadIdx.x;
    wolT[(t & 15) * 16 + (t >> 4)] = wo[t];   // transposed: [d][c]
    if (t < 128) {
        float2 qw = reinterpret_cast<const float2*>(wq)[t];
        float2 kw = reinterpret_cast<const float2*>(wk)[t];
        float2 vw = reinterpret_cast<const float2*>(wv)[t];
        wq2L[t] = pkh2(qw.x * QSCALE_LOG2E, qw.y * QSCALE_LOG2E);
        wk2L[t] = pkh2(kw.x, kw.y);
        wv2L[t] = pkh2(vw.x, vw.y);
    }
    if (t < 16) { bol[t] = bo[t]; gl[t] = gw[t]; blw[t] = bw[t]; }
    if (t < SEQPB) {
        int seq = blockIdx.x * SEQPB + t;
        bases[t] = (seq / d2) * str1 + (seq % d2) * str2;
    }
    __syncthreads();

    const float om[8] = {1.f, 0.31622776601683794f, 0.1f, 0.031622776601683794f,
                         0.01f, 0.0031622776601683794f, 0.001f, 0.00031622776601683794f};

    // ---- phase 1: token load, +posembed, LayerNorm, QKV (fdot2) -> LDS ----
    if constexpr (TPT == 2) {
        // half-channel split: each pair thread owns 8 channels
        int tokIdx = t >> 1;
        int half = t & 1;
        int db   = half * 8;
        int sq = tokIdx & (SEQPB - 1);
        int i  = tokIdx >> LSQ;
        const bf16* src = ((i < HS)
            ? (A + bases[sq] + (size_t)i * tokStride)
            : (R + bases[sq] + (size_t)(i - HS) * tokStride)) + db;
        uint4 u = *reinterpret_cast<const uint4*>(src);
        unsigned uu[4] = {u.x, u.y, u.z, u.w};
        float x[8];
        #pragma unroll
        for (int k = 0; k < 4; ++k) {
            union { unsigned u; float f; } lo, hi2;
            lo.u = uu[k] << 16; hi2.u = uu[k] & 0xffff0000u;
            x[2 * k] = lo.f; x[2 * k + 1] = hi2.f;
        }
        float fi = (float)i;
        #pragma unroll
        for (int k = 0; k < 8; ++k) {
            float sv, cv;
            __sincosf(fi * om[k], &sv, &cv);
            x[k] += half ? cv : sv;
        }
        float s8 = 0.f;
        #pragma unroll
        for (int k = 0; k < 8; ++k) s8 += x[k];
        float m = (s8 + __shfl_xor(s8, 1)) * (1.f / 16.f);
        float v8 = 0.f;
        #pragma unroll
        for (int k = 0; k < 8; ++k) { float d = x[k] - m; v8 = fmaf(d, d, v8); }
        float var = (v8 + __shfl_xor(v8, 1)) * (1.f / 16.f);
        float rs = rsqrtf(var + 1e-5f);

        unsigned xpm[4];
        #pragma unroll
        for (int e = 0; e < 4; ++e) {
            float a0 = (x[2 * e]     - m) * rs * gl[db + 2 * e]     + blw[db + 2 * e];
            float a1 = (x[2 * e + 1] - m) * rs * gl[db + 2 * e + 1] + blw[db + 2 * e + 1];
            xpm[e] = pkh2(a0, a1);
        }
        unsigned xp[8];
        #pragma unroll
        for (int e = 0; e < 4; ++e) {
            unsigned oth = __shfl_xor(xpm[e], 1);
            xp[e]     = half ? oth    : xpm[e];
            xp[e + 4] = half ? xpm[e] : oth;
        }
        float qv[8], kv[8], vv[8];
        #pragma unroll
        for (int dd = 0; dd < 8; ++dd) {
            int d = db + dd;
            float aq = 0.f, ak = 0.f, av = 0.f;
            #pragma unroll
            for (int c2 = 0; c2 < 8; ++c2) {
                aq = fdot2u(xp[c2], wq2L[d * 8 + c2], aq);
                ak = fdot2u(xp[c2], wk2L[d * 8 + c2], ak);
                av = fdot2u(xp[c2], wv2L[d * 8 + c2], av);
            }
            qv[dd] = aq; kv[dd] = ak; vv[dd] = av;
        }
        int row = (sq * S + i) * KROW + (db >> 1);
        uint2* kr = reinterpret_cast<uint2*>(&kU[row]);
        uint2* vr = reinterpret_cast<uint2*>(&vU[row]);
        #pragma unroll
        for (int e = 0; e < 2; ++e) {
            kr[e] = make_uint2(pkh2(kv[4 * e], kv[4 * e + 1]),
                               pkh2(kv[4 * e + 2], kv[4 * e + 3]));
            vr[e] = make_uint2(packbf2(vv[4 * e], vv[4 * e + 1]),
                               packbf2(vv[4 * e + 2], vv[4 * e + 3]));
        }
        if (i < HS) {
            uint2* qr = reinterpret_cast<uint2*>(&qL[(sq * HS + i) * KROW + (db >> 1)]);
            #pragma unroll
            for (int e = 0; e < 2; ++e)
                qr[e] = make_uint2(pkh2(qv[4 * e], qv[4 * e + 1]),
                                   pkh2(qv[4 * e + 2], qv[4 * e + 3]));
        }
    } else {
        // one thread per token, all 16 channels (stage Y)
        int sq = t & (SEQPB - 1);
        int i  = t >> LSQ;
        const bf16* src = (i < HS)
            ? (A + bases[sq] + (size_t)i * tokStride)
            : (R + bases[sq] + (size_t)(i - HS) * tokStride);
        float x[16];
        ld16bf(src, x);
        float fi = (float)i;
        #pragma unroll
        for (int k = 0; k < 8; ++k) {
            float sv, cv;
            __sincosf(fi * om[k], &sv, &cv);
            x[k]     += sv;
            x[k + 8] += cv;
        }
        float m = 0.f;
        #pragma unroll
        for (int c = 0; c < 16; ++c) m += x[c];
        m *= (1.f / 16.f);
        float var = 0.f;
        #pragma unroll
        for (int c = 0; c < 16; ++c) { float d = x[c] - m; var = fmaf(d, d, var); }
        var *= (1.f / 16.f);
        float rs = rsqrtf(var + 1e-5f);
        float xn[16];
        #pragma unroll
        for (int c = 0; c < 16; ++c) xn[c] = (x[c] - m) * rs * gl[c] + blw[c];

        unsigned xp[8];
        #pragma unroll
        for (int c2 = 0; c2 < 8; ++c2) xp[c2] = pkh2(xn[2 * c2], xn[2 * c2 + 1]);

        float qv[16], kv[16], vv[16];
        #pragma unroll
        for (int dd = 0; dd < 16; ++dd) {
            float aq = 0.f, ak = 0.f, av = 0.f;
            #pragma unroll
            for (int c2 = 0; c2 < 8; ++c2) {
                aq = fdot2u(xp[c2], wq2L[dd * 8 + c2], aq);
                ak = fdot2u(xp[c2], wk2L[dd * 8 + c2], ak);
                av = fdot2u(xp[c2], wv2L[dd * 8 + c2], av);
            }
            qv[dd] = aq; kv[dd] = ak; vv[dd] = av;
        }
        int row = (sq * S + i) * KROW;
        uint2* kr = reinterpret_cast<uint2*>(&kU[row]);
        uint2* vr = reinterpret_cast<uint2*>(&vU[row]);
        #pragma unroll
        for (int e = 0; e < 4; ++e) {
            kr[e] = make_uint2(pkh2(kv[4 * e], kv[4 * e + 1]),
                               pkh2(kv[4 * e + 2], kv[4 * e + 3]));
            vr[e] = make_uint2(packbf2(vv[4 * e], vv[4 * e + 1]),
                               packbf2(vv[4 * e + 2], vv[4 * e + 3]));
        }
        if (i < HS) {
            uint2* qr = reinterpret_cast<uint2*>(&qL[(sq * HS + i) * KROW]);
            #pragma unroll
            for (int e = 0; e < 4; ++e)
                qr[e] = make_uint2(pkh2(qv[4 * e], qv[4 * e + 1]),
                                   pkh2(qv[4 * e + 2], qv[4 * e + 3]));
        }
    }
    __syncthreads();

    // ---- phase 2: single-pass softmax (exp2 domain), parity key split,
    //      query-paired packed-FP32 accumulation ----
    int sq2 = t / ITEMS;
    int r   = t % ITEMS;
    int qg  = r >> 4;          // query group (QB queries)
    int hd  = (r >> 1) & 7;    // head
    int half2 = r & 1;         // key parity
    float* oL = reinterpret_cast<float*>(kU);   // overlay after barrier
    {
        unsigned q2[QB];
        f32x2 l2[QP], a0p[QP], a1p[QP];
        #pragma unroll
        for (int qq = 0; qq < QB; ++qq)
            q2[qq] = qL[(sq2 * HS + qg * QB + qq) * KROW + hd];  // scaled f16x2
        #pragma unroll
        for (int m = 0; m < QP; ++m) {
            l2[m] = f2(0.f, 0.f); a0p[m] = f2(0.f, 0.f); a1p[m] = f2(0.f, 0.f);
        }
        const unsigned* kp = &kU[(sq2 * S + half2) * KROW + hd];
        const unsigned* vp = &vU[(sq2 * S + half2) * KROW + hd];
        #pragma unroll 8
        for (int jj = 0; jj < KQ; ++jj) {            // key j = 2*jj + half2
            unsigned ku = kp[jj * 2 * KROW];
            unsigned vu = vp[jj * 2 * KROW];
            union { unsigned u; float f; } v0, v1;
            v0.u = vu << 16; v1.u = vu & 0xffff0000u;
            f32x2 v00 = f2(v0.f, v0.f);
            f32x2 v11 = f2(v1.f, v1.f);
            #pragma unroll
            for (int m = 0; m < QP; ++m) {
                f32x2 p2;
                p2.x = __builtin_amdgcn_exp2f(fdot2u(q2[2 * m], ku, 0.f));
                p2.y = __builtin_amdgcn_exp2f(fdot2u(q2[2 * m + 1], ku, 0.f));
                l2[m] += p2;                                    // v_pk_add_f32
                a0p[m] = __builtin_elementwise_fma(p2, v00, a0p[m]);  // v_pk_fma_f32
                a1p[m] = __builtin_elementwise_fma(p2, v11, a1p[m]);
            }
        }
        #pragma unroll
        for (int m = 0; m < QP; ++m) {
            l2[m].x  += __shfl_xor(l2[m].x, 1);  l2[m].y  += __shfl_xor(l2[m].y, 1);
            a0p[m].x += __shfl_xor(a0p[m].x, 1); a0p[m].y += __shfl_xor(a0p[m].y, 1);
            a1p[m].x += __shfl_xor(a1p[m].x, 1); a1p[m].y += __shfl_xor(a1p[m].y, 1);
        }
        __syncthreads();   // all k/q reads done in every thread; kU reusable as oL
        if (half2 == 0) {
            #pragma unroll
            for (int m = 0; m < QP; ++m) {
                float inv0 = 1.f / l2[m].x;
                float inv1 = 1.f / l2[m].y;
                *reinterpret_cast<float2*>(
                    &oL[(sq2 * HS + qg * QB + 2 * m) * QROW + 2 * hd]) =
                    make_float2(a0p[m].x * inv0, a1p[m].x * inv0);
                *reinterpret_cast<float2*>(
                    &oL[(sq2 * HS + qg * QB + 2 * m + 1) * QROW + 2 * hd]) =
                    make_float2(a0p[m].y * inv1, a1p[m].y * inv1);
            }
        }
    }
    __syncthreads();

    // ---- phase 3: out-proj, in-place bf16x2 write; sq fastest for lines ----
    #pragma unroll
    for (int rep = 0; rep < NW3; ++rep) {
        int idx = t + rep * 256;          // < SEQPB*HS*8
        int cp  = idx & 7;                // channel pair
        int g   = idx >> 3;
        int sq3 = g & (SEQPB - 1);
        int tok = g >> LSQ;
        const float* orow = &oL[(sq3 * HS + tok) * QROW];
        float acc0 = bol[2 * cp], acc1 = bol[2 * cp + 1];
        #pragma unroll
        for (int d = 0; d < 16; ++d) {
            acc0 = fmaf(orow[d], wolT[d * 16 + 2 * cp], acc0);
            acc1 = fmaf(orow[d], wolT[d * 16 + 2 * cp + 1], acc1);
        }
        int off = bases[sq3] + tok * tokStride;
        *reinterpret_cast<unsigned*>(A + off + 2 * cp) = packbf2(acc0, acc1);
        if constexpr (F16OUT)
            A16[(off >> 1) + cp] = pkh2(acc0, acc1);   // f16 shadow for conv_out
    }
}

// ---------------------------------------------------------------------------
// Kernel 5: out = hidden + conv(rest).  Input is the f16x2 shadow (A16);
// block stages its 6 rows into LDS once (pure copy), conv reads ds_read_b64.
// ---------------------------------------------------------------------------
__global__ __launch_bounds__(256) void conv_out_kernel(
    const unsigned* __restrict__ A16, const float* __restrict__ hid,
    const float* __restrict__ pw, const float* __restrict__ pb,
    float* __restrict__ out)
{
    __shared__ unsigned w2l[9 * 128];   // [tap][oc][ic/2] f16x2
    __shared__ float bl[16];
    __shared__ __align__(16) unsigned stg[6 * 64 * 10];

    int t = threadIdx.x;
    if (t < 128) {
        int oc = t & 15, c2 = t >> 4;
        #pragma unroll
        for (int k = 0; k < 9; ++k)
            w2l[k * 128 + oc * 8 + c2] =
                pkh2(pw[(oc * 16 + 2 * c2) * 9 + k],
                     pw[(oc * 16 + 2 * c2 + 1) * 9 + k]);
    }
    if (t < 16) bl[t] = pb[t];

    int gid = blockIdx.x * 256 + t;   // 0 .. NIMG*PIX-1
    int wi = gid & 63, hi = (gid >> 6) & 63;
    int r0 = hi & ~3;
    int img = gid >> 12;
    const unsigned* inp = A16 + ((size_t)img << 15);   // 32768 uints / image

    #pragma unroll
    for (int pass = 0; pass < 2; ++pass) {
        int s = t + pass * 256;
        if (s < 384) {
            int px = s & 63, rr = s >> 6;
            int y  = r0 - 1 + rr;
            if ((unsigned)y < 64u) {
                const uint4* sp = reinterpret_cast<const uint4*>(
                    inp + (((y << 6) + px) << 3));
                uint4 u0 = sp[0], u1 = sp[1];
                uint2* dst = reinterpret_cast<uint2*>(&stg[(rr * 64 + px) * 10]);
                dst[0] = make_uint2(u0.x, u0.y);
                dst[1] = make_uint2(u0.z, u0.w);
                dst[2] = make_uint2(u1.x, u1.y);
                dst[3] = make_uint2(u1.z, u1.w);
            }
        }
    }
    __syncthreads();

    int rb = hi & 3;
    float acc[16];
    #pragma unroll
    for (int oc = 0; oc < 16; ++oc) acc[oc] = bl[oc];

    #pragma unroll
    for (int ky = 0; ky < 3; ++ky) {
        int y = hi + ky - 1;
        if ((unsigned)y >= 64u) continue;
        int rr = rb + ky;
        #pragma unroll
        for (int kx = 0; kx < 3; ++kx) {
            int xx = wi + kx - 1;
            if ((unsigned)xx >= 64u) continue;
            const uint2* pp = reinterpret_cast<const uint2*>(&stg[(rr * 64 + xx) * 10]);
            uint2 p0 = pp[0], p1 = pp[1], p2 = pp[2], p3 = pp[3];
            unsigned xp[8] = {p0.x, p0.y, p1.x, p1.y, p2.x, p2.y, p3.x, p3.y};
            const unsigned* wt = &w2l[(ky * 3 + kx) * 128];
            #pragma unroll
            for (int oc = 0; oc < 16; ++oc) {
                float a = acc[oc];
                #pragma unroll
                for (int c2 = 0; c2 < 8; ++c2)
                    a = fdot2u(xp[c2], wt[oc * 8 + c2], a);
                acc[oc] = a;
            }
        }
    }
    size_t off = ((size_t)gid) << 4;
    float hv[16];
    ld16f(hid + off, hv);
    float res[16];
    #pragma unroll
    for (int k = 0; k < 16; ++k) res[k] = acc[k] + hv[k];
    st16f(out + off, res);
}

// ---------------------------------------------------------------------------
extern "C" void kernel_launch(void* const* d_in, const int* in_sizes, int n_in,
                              void* d_out, int out_size, void* d_ws, size_t ws_size,
                              hipStream_t stream) {
    const float* hid  = (const float*)d_in[0];
    const float* ref  = (const float*)d_in[1];
    const float* emb  = (const float*)d_in[2];
    const float* ciw  = (const float*)d_in[3];
    const float* cib  = (const float*)d_in[4];
    const float* e1w  = (const float*)d_in[5];
    const float* e1b  = (const float*)d_in[6];
    const float* e2w  = (const float*)d_in[7];
    const float* e2b  = (const float*)d_in[8];
    const float* wqx  = (const float*)d_in[9];
    const float* wkx  = (const float*)d_in[10];
    const float* wvx  = (const float*)d_in[11];
    const float* wox  = (const float*)d_in[12];
    const float* box_ = (const float*)d_in[13];
    const float* wqy  = (const float*)d_in[14];
    const float* wky  = (const float*)d_in[15];
    const float* wvy  = (const float*)d_in[16];
    const float* woy  = (const float*)d_in[17];
    const float* boy  = (const float*)d_in[18];
    const float* wqt  = (const float*)d_in[19];
    const float* wkt  = (const float*)d_in[20];
    const float* wvt  = (const float*)d_in[21];
    const float* wot  = (const float*)d_in[22];
    const float* bot  = (const float*)d_in[23];
    const float* ng   = (const float*)d_in[24];
    const float* nb   = (const float*)d_in[25];
    const float* pjw  = (const float*)d_in[26];
    const float* pjb  = (const float*)d_in[27];

    bf16* A = (bf16*)d_ws;     // 4 MiB in workspace
    unsigned* A16 = (unsigned*)((char*)d_ws + (4 << 20));  // 4 MiB f16 shadow
    bf16* R = (bf16*)d_out;    // 4 MiB scratch inside the 8 MiB f32 output buf
                               // (fully overwritten by conv_out at the end)

    conv_in_kernel<<<(2 * NIMG * PIX) / 256, 256, 0, stream>>>(
        hid, ref, ciw, cib, emb, e1w, e1b, e2w, e2b, A, R);

    // Stage X: seq=(b,f,h), S=2W=128, token stride 16 (contiguous rows), TPT=2
    attn_kernel<128, 1, 8, false><<<BB * FF * HH, 256, 0, stream>>>(
        A, R, nullptr, 1, WW * CC, 0, CC, wqx, wkx, wvx, wox, box_, ng, nb);
    // Stage Y: seq=(b,f,w), S=2H=128, tok stride W*C; 2 consecutive w, TPT=1
    attn_kernel<128, 2, 4, false><<<(BB * FF * WW) / 2, 256, 0, stream>>>(
        A, R, nullptr, WW, IMGSZ, CC, WW * CC, wqy, wky, wvy, woy, boy, ng, nb);
    // Stage T: seq=(b,h,w), S=2F=32, tok stride H*W*C; 4 consecutive w, TPT=2
    // writes bf16 A (unused afterwards) + f16 shadow A16 for conv_out
    attn_kernel<32, 4, 8, true><<<(BB * HH * WW) / 4, 256, 0, stream>>>(
        A, R, A16, HH * WW, FF * IMGSZ, CC, IMGSZ, wqt, wkt, wvt, wot, bot, ng, nb);

    conv_out_kernel<<<(NIMG * PIX) / 256, 256, 0, stream>>>(A16, hid, pjw, pjb, (float*)d_out);
}

// Round 7
// 223.954 us; speedup vs baseline: 1.1210x; 1.0413x over previous
//
#include <hip/hip_runtime.h>
#include <hip/hip_bf16.h>

typedef __hip_bfloat16 bf16;
// match the builtin's own return type (__fp16 ext_vector(2)) exactly
using hf2 = decltype(__builtin_amdgcn_cvt_pkrtz(0.f, 0.f));
typedef float f32x2 __attribute__((ext_vector_type(2)));
typedef _Float16 v4h __attribute__((ext_vector_type(4)));   // MFMA A/B frag
typedef float v4f __attribute__((ext_vector_type(4)));      // MFMA C/D frag

// ---------------------------------------------------------------------------
// Problem constants
// ---------------------------------------------------------------------------
#define BB   2
#define FF   16
#define HH   64
#define WW   64
#define CC   16     // in/out channels == MID
#define NIMG (BB*FF)        // 32
#define PIX  (HH*WW)        // 4096
#define IMGSZ (PIX*CC)      // 65536 elements per image (channel-last)

// scale(=1/sqrt(2)) * log2(e): folded into staged Wq; softmax uses raw v_exp_f32
#define QSCALE_LOG2E 1.0201394f

// ---- packed f16x2 helpers (v_cvt_pkrtz_f16_f32 / v_dot2_f32_f16) ----
__device__ __forceinline__ unsigned pkh2(float a, float b) {
    union { hf2 h; unsigned u; } x;
    x.h = __builtin_amdgcn_cvt_pkrtz(a, b);
    return x.u;
}
__device__ __forceinline__ float fdot2u(unsigned a, unsigned b, float c) {
    union { unsigned u; hf2 h; } A, B;
    A.u = a; B.u = b;
    return __builtin_amdgcn_fdot2(A.h, B.h, c, false);
}
__device__ __forceinline__ f32x2 f2(float a, float b) {
    f32x2 r; r.x = a; r.y = b; return r;
}

// ---- 16-element bf16 I/O ----
__device__ __forceinline__ void ld16bf(const bf16* p, float* x) {
    const uint4* p4 = reinterpret_cast<const uint4*>(p);
    uint4 u0 = p4[0], u1 = p4[1];
    unsigned uu[8] = {u0.x, u0.y, u0.z, u0.w, u1.x, u1.y, u1.z, u1.w};
    #pragma unroll
    for (int k = 0; k < 8; ++k) {
        union { unsigned u; float f; } lo, hi;
        lo.u = uu[k] << 16;
        hi.u = uu[k] & 0xffff0000u;
        x[2 * k] = lo.f;
        x[2 * k + 1] = hi.f;
    }
}

// ---- 16-element fp32 I/O ----
__device__ __forceinline__ void ld16f(const float* p, float* x) {
    const float4* p4 = reinterpret_cast<const float4*>(p);
    #pragma unroll
    for (int q = 0; q < 4; ++q) {
        float4 v = p4[q];
        x[4 * q] = v.x; x[4 * q + 1] = v.y; x[4 * q + 2] = v.z; x[4 * q + 3] = v.w;
    }
}

__device__ __forceinline__ unsigned packbf2(float a, float b) {
    union { bf16 h[2]; unsigned u; } pk;
    pk.h[0] = __float2bfloat16(a);
    pk.h[1] = __float2bfloat16(b);
    return pk.u;
}

// Conv weight prepack into MFMA-B layout: wB[(tap*4+chunk)*16+oc] = 4 f16 of
// w[oc][ic=chunk*4..+3][tap].  576 8-byte entries (4.6 KB).
__device__ __forceinline__ void stage_wB(const float* __restrict__ w,
                                         unsigned* __restrict__ wB, int t) {
    for (int e = t; e < 576; e += 256) {
        int oc = e & 15;
        int c  = (e >> 4) & 3;
        int s  = e >> 6;                 // tap 0..8
        const float* wp = w + (oc * 16 + c * 4) * 9 + s;   // ic stride = 9
        wB[e * 2]     = pkh2(wp[0],  wp[9]);
        wB[e * 2 + 1] = pkh2(wp[18], wp[27]);
    }
}

// per-tap LDS byte... (uint) offset inside the halo-staged tile:
// taps s=0..8 -> (dy,dx) = (s/3-1, s%3-1); corner-biased base => offset
// ((s/3)*66 + s%3) * 12 uints (compile-time per unrolled step).
#define TAP_OFF(s) ((((s) / 3) * 66 + ((s) % 3)) * 12)

// ---------------------------------------------------------------------------
// Kernel 1 (MFMA): conv stem on hidden (->A) and ref (->R, + fused emb-MLP).
// Block = 4 rows of one image-half (4 waves; wave w owns row r0+w, 4 tiles of
// 16 px).  Halo-staged input 6x66 px, f16x2-packed, 12-uint pixel slots.
// Per wave: 9 B-frag ds_read_b64 (shared across tiles) + per tile 9 A-frag
// ds_read_b64 (base + const offset) + 9 v_mfma_f32_16x16x16_f16.
// ---------------------------------------------------------------------------
__global__ __launch_bounds__(256) void conv_in_kernel(
    const float* __restrict__ hid, const float* __restrict__ ref,
    const float* __restrict__ cw, const float* __restrict__ cb,
    const float* __restrict__ emb,
    const float* __restrict__ e1w, const float* __restrict__ e1b,
    const float* __restrict__ e2w, const float* __restrict__ e2b,
    bf16* __restrict__ A, bf16* __restrict__ R)
{
    __shared__ __align__(16) unsigned stg[6 * 66 * 12];   // 19008 B
    __shared__ __align__(16) unsigned wB[1152];           // 4608 B
    __shared__ float bl[16], hl[16], el[16];

    int t = threadIdx.x;
    int bid = blockIdx.x;          // 1024 blocks
    int rg   = bid & 15;
    int img2 = bid >> 4;           // 0..63, block-uniform
    int isref = img2 >> 5;
    int img   = img2 & 31;
    int bi    = img >> 4;
    int r0    = rg << 2;

    stage_wB(cw, wB, t);
    if (t < 16) bl[t] = cb[t];

    if (isref) {   // block-uniform branch: internal barriers safe
        float* red = reinterpret_cast<float*>(stg);   // overlay, freed below
        {
            int o = t >> 4, seg = t & 15;
            const float* er = emb + bi * 512 + seg * 32;
            const float* wr = e1w + o * 512 + seg * 32;
            float p = 0.f;
            #pragma unroll
            for (int k = 0; k < 32; ++k) p = fmaf(er[k], wr[k], p);
            red[t] = p;
        }
        __syncthreads();
        if (t < 16) {
            float acc = e1b[t];
            #pragma unroll
            for (int s = 0; s < 16; ++s) acc += red[t * 16 + s];
            hl[t] = acc / (1.f + __expf(-acc));   // silu
        }
        __syncthreads();
        if (t < 16) {
            float acc = e2b[t];
            #pragma unroll
            for (int k = 0; k < 16; ++k) acc = fmaf(hl[k], e2w[t * 16 + k], acc);
            el[t] = acc;
        }
        __syncthreads();   // red region free
    }

    // ---- stage 6 halo rows (r0-1..r0+4) x 66 cols, f16x2-packed ----
    const float* inp = (isref ? ref : hid) + (size_t)img * IMGSZ;
    for (int s2 = t; s2 < 396; s2 += 256) {
        int rr = s2 / 66, xi = s2 - rr * 66;
        int y = r0 - 1 + rr, px = xi - 1;
        uint4* dst = reinterpret_cast<uint4*>(&stg[(rr * 66 + xi) * 12]);
        if ((unsigned)y < 64u && (unsigned)px < 64u) {
            float xv[16];
            ld16f(inp + (((y << 6) + px) << 4), xv);
            dst[0] = make_uint4(pkh2(xv[0], xv[1]),  pkh2(xv[2], xv[3]),
                                pkh2(xv[4], xv[5]),  pkh2(xv[6], xv[7]));
            dst[1] = make_uint4(pkh2(xv[8], xv[9]),  pkh2(xv[10], xv[11]),
                                pkh2(xv[12], xv[13]), pkh2(xv[14], xv[15]));
        } else {
            dst[0] = make_uint4(0, 0, 0, 0);
            dst[1] = make_uint4(0, 0, 0, 0);
        }
    }
    __syncthreads();

    // ---- implicit-GEMM conv via MFMA ----
    int l  = t & 63, w = t >> 6;
    int oc = l & 15, c = l >> 4;      // B col / D col = oc; k-chunk = c
    int y  = r0 + w;

    v4h bf[9];
    int cb2 = c * 32 + oc * 2;
    #pragma unroll
    for (int s = 0; s < 9; ++s)
        bf[s] = *reinterpret_cast<const v4h*>(&wB[s * 128 + cb2]);

    float bias = bl[oc] + (isref ? el[oc] : 0.f);
    v4f binit; binit[0] = bias; binit[1] = bias; binit[2] = bias; binit[3] = bias;

    bf16* op = (isref ? R : A) + (size_t)img * IMGSZ;

    #pragma unroll
    for (int xq = 0; xq < 4; ++xq) {
        int ab = (w * 66 + xq * 16 + (l & 15)) * 12 + 2 * c;  // corner-biased
        v4f acc = binit;
        #pragma unroll
        for (int s = 0; s < 9; ++s) {
            v4h af = *reinterpret_cast<const v4h*>(&stg[ab + TAP_OFF(s)]);
            acc = __builtin_amdgcn_mfma_f32_16x16x16f16(af, bf[s], acc, 0, 0, 0);
        }
        #pragma unroll
        for (int g = 0; g < 4; ++g) {
            int x = xq * 16 + c * 4 + g;          // D row = c*4+g
            op[(((y << 6) + x) << 4) + oc] = __float2bfloat16(acc[g]);
        }
    }
}

// ---------------------------------------------------------------------------
// Attention stage. 256 threads; TPT = 256/(SEQPB*S) threads per token.
// Sequence s: tokens j<S/2 from A, j>=S/2 from R.
//   token j elem offset = (s/d2)*str1 + (s%d2)*str2 + j*tokStride
// Output (first S/2 tokens): bf16 in-place into A; the T stage instead writes
// ONLY the f16x2 shadow (A16) consumed by the MFMA conv_out.
// ---------------------------------------------------------------------------
template<int S, int SEQPB, int MINW, bool F16OUT>
__global__ __launch_bounds__(256, MINW) void attn_kernel(
    bf16* __restrict__ A, const bf16* __restrict__ R,
    unsigned* __restrict__ A16,
    int d2, int str1, int str2, int tokStride,
    const float* __restrict__ wq, const float* __restrict__ wk,
    const float* __restrict__ wv, const float* __restrict__ wo,
    const float* __restrict__ bo, const float* __restrict__ gw,
    const float* __restrict__ bw)
{
    constexpr int HS  = S / 2;
    constexpr int KQ  = S / 2;
    constexpr int TPT = 256 / (SEQPB * S);
    constexpr int ITEMS = 256 / SEQPB;
    constexpr int NQG = ITEMS / 16;
    constexpr int QB  = HS / NQG;
    constexpr int QP  = QB / 2;
    constexpr int KROW = 10;
    constexpr int QROW = 20;
    constexpr int LSQ = (SEQPB == 1) ? 0 : ((SEQPB == 2) ? 1 : 2);
    constexpr int NW3 = SEQPB * HS * 8 / 256;

    __shared__ float wolT[256];
    __shared__ unsigned wq2L[128], wk2L[128], wv2L[128];
    __shared__ float bol[16], gl[16], blw[16];
    __shared__ __align__(16) unsigned kU[SEQPB * S * KROW];
    __shared__ __align__(16) unsigned vU[SEQPB * S * KROW];
    __shared__ __align__(16) unsigned qL[SEQPB * HS * KROW];
    __shared__ int bases[SEQPB];

    int t = threadIdx.x;
    wolT[(t & 15) * 16 + (t >> 4)] = wo[t];
    if (t < 128) {
        float2 qw = reinterpret_cast<const float2*>(wq)[t];
        float2 kw = reinterpret_cast<const float2*>(wk)[t];
        float2 vw = reinterpret_cast<const float2*>(wv)[t];
        wq2L[t] = pkh2(qw.x * QSCALE_LOG2E, qw.y * QSCALE_LOG2E);
        wk2L[t] = pkh2(kw.x, kw.y);
        wv2L[t] = pkh2(vw.x, vw.y);
    }
    if (t < 16) { bol[t] = bo[t]; gl[t] = gw[t]; blw[t] = bw[t]; }
    if (t < SEQPB) {
        int seq = blockIdx.x * SEQPB + t;
        bases[t] = (seq / d2) * str1 + (seq % d2) * str2;
    }
    __syncthreads();

    const float om[8] = {1.f, 0.31622776601683794f, 0.1f, 0.031622776601683794f,
                         0.01f, 0.0031622776601683794f, 0.001f, 0.00031622776601683794f};

    // ---- phase 1: token load, +posembed, LayerNorm, QKV (fdot2) -> LDS ----
    if constexpr (TPT == 2) {
        int tokIdx = t >> 1;
        int half = t & 1;
        int db   = half * 8;
        int sq = tokIdx & (SEQPB - 1);
        int i  = tokIdx >> LSQ;
        const bf16* src = ((i < HS)
            ? (A + bases[sq] + (size_t)i * tokStride)
            : (R + bases[sq] + (size_t)(i - HS) * tokStride)) + db;
        uint4 u = *reinterpret_cast<const uint4*>(src);
        unsigned uu[4] = {u.x, u.y, u.z, u.w};
        float x[8];
        #pragma unroll
        for (int k = 0; k < 4; ++k) {
            union { unsigned u; float f; } lo, hi2;
            lo.u = uu[k] << 16; hi2.u = uu[k] & 0xffff0000u;
            x[2 * k] = lo.f; x[2 * k + 1] = hi2.f;
        }
        float fi = (float)i;
        #pragma unroll
        for (int k = 0; k < 8; ++k) {
            float sv, cv;
            __sincosf(fi * om[k], &sv, &cv);
            x[k] += half ? cv : sv;
        }
        float s8 = 0.f;
        #pragma unroll
        for (int k = 0; k < 8; ++k) s8 += x[k];
        float m = (s8 + __shfl_xor(s8, 1)) * (1.f / 16.f);
        float v8 = 0.f;
        #pragma unroll
        for (int k = 0; k < 8; ++k) { float d = x[k] - m; v8 = fmaf(d, d, v8); }
        float var = (v8 + __shfl_xor(v8, 1)) * (1.f / 16.f);
        float rs = rsqrtf(var + 1e-5f);

        unsigned xpm[4];
        #pragma unroll
        for (int e = 0; e < 4; ++e) {
            float a0 = (x[2 * e]     - m) * rs * gl[db + 2 * e]     + blw[db + 2 * e];
            float a1 = (x[2 * e + 1] - m) * rs * gl[db + 2 * e + 1] + blw[db + 2 * e + 1];
            xpm[e] = pkh2(a0, a1);
        }
        unsigned xp[8];
        #pragma unroll
        for (int e = 0; e < 4; ++e) {
            unsigned oth = __shfl_xor(xpm[e], 1);
            xp[e]     = half ? oth    : xpm[e];
            xp[e + 4] = half ? xpm[e] : oth;
        }
        float qv[8], kv[8], vv[8];
        #pragma unroll
        for (int dd = 0; dd < 8; ++dd) {
            int d = db + dd;
            float aq = 0.f, ak = 0.f, av = 0.f;
            #pragma unroll
            for (int c2 = 0; c2 < 8; ++c2) {
                aq = fdot2u(xp[c2], wq2L[d * 8 + c2], aq);
                ak = fdot2u(xp[c2], wk2L[d * 8 + c2], ak);
                av = fdot2u(xp[c2], wv2L[d * 8 + c2], av);
            }
            qv[dd] = aq; kv[dd] = ak; vv[dd] = av;
        }
        int row = (sq * S + i) * KROW + (db >> 1);
        uint2* kr = reinterpret_cast<uint2*>(&kU[row]);
        uint2* vr = reinterpret_cast<uint2*>(&vU[row]);
        #pragma unroll
        for (int e = 0; e < 2; ++e) {
            kr[e] = make_uint2(pkh2(kv[4 * e], kv[4 * e + 1]),
                               pkh2(kv[4 * e + 2], kv[4 * e + 3]));
            vr[e] = make_uint2(packbf2(vv[4 * e], vv[4 * e + 1]),
                               packbf2(vv[4 * e + 2], vv[4 * e + 3]));
        }
        if (i < HS) {
            uint2* qr = reinterpret_cast<uint2*>(&qL[(sq * HS + i) * KROW + (db >> 1)]);
            #pragma unroll
            for (int e = 0; e < 2; ++e)
                qr[e] = make_uint2(pkh2(qv[4 * e], qv[4 * e + 1]),
                                   pkh2(qv[4 * e + 2], qv[4 * e + 3]));
        }
    } else {
        int sq = t & (SEQPB - 1);
        int i  = t >> LSQ;
        const bf16* src = (i < HS)
            ? (A + bases[sq] + (size_t)i * tokStride)
            : (R + bases[sq] + (size_t)(i - HS) * tokStride);
        float x[16];
        ld16bf(src, x);
        float fi = (float)i;
        #pragma unroll
        for (int k = 0; k < 8; ++k) {
            float sv, cv;
            __sincosf(fi * om[k], &sv, &cv);
            x[k]     += sv;
            x[k + 8] += cv;
        }
        float m = 0.f;
        #pragma unroll
        for (int c = 0; c < 16; ++c) m += x[c];
        m *= (1.f / 16.f);
        float var = 0.f;
        #pragma unroll
        for (int c = 0; c < 16; ++c) { float d = x[c] - m; var = fmaf(d, d, var); }
        var *= (1.f / 16.f);
        float rs = rsqrtf(var + 1e-5f);
        float xn[16];
        #pragma unroll
        for (int c = 0; c < 16; ++c) xn[c] = (x[c] - m) * rs * gl[c] + blw[c];

        unsigned xp[8];
        #pragma unroll
        for (int c2 = 0; c2 < 8; ++c2) xp[c2] = pkh2(xn[2 * c2], xn[2 * c2 + 1]);

        float qv[16], kv[16], vv[16];
        #pragma unroll
        for (int dd = 0; dd < 16; ++dd) {
            float aq = 0.f, ak = 0.f, av = 0.f;
            #pragma unroll
            for (int c2 = 0; c2 < 8; ++c2) {
                aq = fdot2u(xp[c2], wq2L[dd * 8 + c2], aq);
                ak = fdot2u(xp[c2], wk2L[dd * 8 + c2], ak);
                av = fdot2u(xp[c2], wv2L[dd * 8 + c2], av);
            }
            qv[dd] = aq; kv[dd] = ak; vv[dd] = av;
        }
        int row = (sq * S + i) * KROW;
        uint2* kr = reinterpret_cast<uint2*>(&kU[row]);
        uint2* vr = reinterpret_cast<uint2*>(&vU[row]);
        #pragma unroll
        for (int e = 0; e < 4; ++e) {
            kr[e] = make_uint2(pkh2(kv[4 * e], kv[4 * e + 1]),
                               pkh2(kv[4 * e + 2], kv[4 * e + 3]));
            vr[e] = make_uint2(packbf2(vv[4 * e], vv[4 * e + 1]),
                               packbf2(vv[4 * e + 2], vv[4 * e + 3]));
        }
        if (i < HS) {
            uint2* qr = reinterpret_cast<uint2*>(&qL[(sq * HS + i) * KROW]);
            #pragma unroll
            for (int e = 0; e < 4; ++e)
                qr[e] = make_uint2(pkh2(qv[4 * e], qv[4 * e + 1]),
                                   pkh2(qv[4 * e + 2], qv[4 * e + 3]));
        }
    }
    __syncthreads();

    // ---- phase 2: single-pass softmax (exp2 domain), parity key split ----
    int sq2 = t / ITEMS;
    int r   = t % ITEMS;
    int qg  = r >> 4;
    int hd  = (r >> 1) & 7;
    int half2 = r & 1;
    float* oL = reinterpret_cast<float*>(kU);
    {
        unsigned q2[QB];
        f32x2 l2[QP], a0p[QP], a1p[QP];
        #pragma unroll
        for (int qq = 0; qq < QB; ++qq)
            q2[qq] = qL[(sq2 * HS + qg * QB + qq) * KROW + hd];
        #pragma unroll
        for (int m = 0; m < QP; ++m) {
            l2[m] = f2(0.f, 0.f); a0p[m] = f2(0.f, 0.f); a1p[m] = f2(0.f, 0.f);
        }
        const unsigned* kp = &kU[(sq2 * S + half2) * KROW + hd];
        const unsigned* vp = &vU[(sq2 * S + half2) * KROW + hd];
        #pragma unroll 8
        for (int jj = 0; jj < KQ; ++jj) {
            unsigned ku = kp[jj * 2 * KROW];
            unsigned vu = vp[jj * 2 * KROW];
            union { unsigned u; float f; } v0, v1;
            v0.u = vu << 16; v1.u = vu & 0xffff0000u;
            f32x2 v00 = f2(v0.f, v0.f);
            f32x2 v11 = f2(v1.f, v1.f);
            #pragma unroll
            for (int m = 0; m < QP; ++m) {
                f32x2 p2;
                p2.x = __builtin_amdgcn_exp2f(fdot2u(q2[2 * m], ku, 0.f));
                p2.y = __builtin_amdgcn_exp2f(fdot2u(q2[2 * m + 1], ku, 0.f));
                l2[m] += p2;
                a0p[m] = __builtin_elementwise_fma(p2, v00, a0p[m]);
                a1p[m] = __builtin_elementwise_fma(p2, v11, a1p[m]);
            }
        }
        #pragma unroll
        for (int m = 0; m < QP; ++m) {
            l2[m].x  += __shfl_xor(l2[m].x, 1);  l2[m].y  += __shfl_xor(l2[m].y, 1);
            a0p[m].x += __shfl_xor(a0p[m].x, 1); a0p[m].y += __shfl_xor(a0p[m].y, 1);
            a1p[m].x += __shfl_xor(a1p[m].x, 1); a1p[m].y += __shfl_xor(a1p[m].y, 1);
        }
        __syncthreads();
        if (half2 == 0) {
            #pragma unroll
            for (int m = 0; m < QP; ++m) {
                float inv0 = 1.f / l2[m].x;
                float inv1 = 1.f / l2[m].y;
                *reinterpret_cast<float2*>(
                    &oL[(sq2 * HS + qg * QB + 2 * m) * QROW + 2 * hd]) =
                    make_float2(a0p[m].x * inv0, a1p[m].x * inv0);
                *reinterpret_cast<float2*>(
                    &oL[(sq2 * HS + qg * QB + 2 * m + 1) * QROW + 2 * hd]) =
                    make_float2(a0p[m].y * inv1, a1p[m].y * inv1);
            }
        }
    }
    __syncthreads();

    // ---- phase 3: out-proj; bf16 in-place (X/Y) or f16 shadow only (T) ----
    #pragma unroll
    for (int rep = 0; rep < NW3; ++rep) {
        int idx = t + rep * 256;
        int cp  = idx & 7;
        int g   = idx >> 3;
        int sq3 = g & (SEQPB - 1);
        int tok = g >> LSQ;
        const float* orow = &oL[(sq3 * HS + tok) * QROW];
        float acc0 = bol[2 * cp], acc1 = bol[2 * cp + 1];
        #pragma unroll
        for (int d = 0; d < 16; ++d) {
            acc0 = fmaf(orow[d], wolT[d * 16 + 2 * cp], acc0);
            acc1 = fmaf(orow[d], wolT[d * 16 + 2 * cp + 1], acc1);
        }
        int off = bases[sq3] + tok * tokStride;
        if constexpr (F16OUT)
            A16[(off >> 1) + cp] = pkh2(acc0, acc1);   // conv_out consumes f16
        else
            *reinterpret_cast<unsigned*>(A + off + 2 * cp) = packbf2(acc0, acc1);
    }
}

// ---------------------------------------------------------------------------
// Kernel 5 (MFMA): out = hidden + conv(rest).  Input = A16 f16x2 shadow.
// Block = 2 rows (4 waves, wave w owns tiles w*2, w*2+1); halo stage is a
// pure copy (no cvt).  Same implicit-GEMM structure as conv_in.
// ---------------------------------------------------------------------------
__global__ __launch_bounds__(256) void conv_out_kernel(
    const unsigned* __restrict__ A16, const float* __restrict__ hid,
    const float* __restrict__ pw, const float* __restrict__ pb,
    float* __restrict__ out)
{
    __shared__ __align__(16) unsigned stg[4 * 66 * 12];   // 12672 B
    __shared__ __align__(16) unsigned wB[1152];
    __shared__ float bl[16];

    int t = threadIdx.x;
    int bid = blockIdx.x;          // 1024 blocks = 32 img x 32 row-pairs
    int rg  = bid & 31;
    int img = bid >> 5;
    int r0  = rg << 1;

    stage_wB(pw, wB, t);
    if (t < 16) bl[t] = pb[t];

    const unsigned* inp = A16 + ((size_t)img << 15);   // 8 uints / pixel
    for (int s2 = t; s2 < 264; s2 += 256) {            // 4 rows x 66
        int rr = s2 / 66, xi = s2 - rr * 66;
        int y = r0 - 1 + rr, px = xi - 1;
        uint4* dst = reinterpret_cast<uint4*>(&stg[(rr * 66 + xi) * 12]);
        if ((unsigned)y < 64u && (unsigned)px < 64u) {
            const uint4* sp = reinterpret_cast<const uint4*>(
                inp + (((y << 6) + px) << 3));
            dst[0] = sp[0];
            dst[1] = sp[1];
        } else {
            dst[0] = make_uint4(0, 0, 0, 0);
            dst[1] = make_uint4(0, 0, 0, 0);
        }
    }
    __syncthreads();

    int l  = t & 63, w = t >> 6;
    int oc = l & 15, c = l >> 4;

    v4h bf[9];
    int cb2 = c * 32 + oc * 2;
    #pragma unroll
    for (int s = 0; s < 9; ++s)
        bf[s] = *reinterpret_cast<const v4h*>(&wB[s * 128 + cb2]);

    float bias = bl[oc];
    v4f binit; binit[0] = bias; binit[1] = bias; binit[2] = bias; binit[3] = bias;
    size_t obase = (size_t)img * IMGSZ;

    #pragma unroll
    for (int tq = 0; tq < 2; ++tq) {
        int tile = w * 2 + tq;
        int ro = tile >> 2, xq = tile & 3;
        int y  = r0 + ro;
        int ab = (ro * 66 + xq * 16 + (l & 15)) * 12 + 2 * c;
        v4f acc = binit;
        #pragma unroll
        for (int s = 0; s < 9; ++s) {
            v4h af = *reinterpret_cast<const v4h*>(&stg[ab + TAP_OFF(s)]);
            acc = __builtin_amdgcn_mfma_f32_16x16x16f16(af, bf[s], acc, 0, 0, 0);
        }
        #pragma unroll
        for (int g = 0; g < 4; ++g) {
            int x = xq * 16 + c * 4 + g;
            size_t o = obase + (size_t)(((y << 6) + x) << 4) + oc;
            out[o] = acc[g] + hid[o];
        }
    }
}

// ---------------------------------------------------------------------------
extern "C" void kernel_launch(void* const* d_in, const int* in_sizes, int n_in,
                              void* d_out, int out_size, void* d_ws, size_t ws_size,
                              hipStream_t stream) {
    const float* hid  = (const float*)d_in[0];
    const float* ref  = (const float*)d_in[1];
    const float* emb  = (const float*)d_in[2];
    const float* ciw  = (const float*)d_in[3];
    const float* cib  = (const float*)d_in[4];
    const float* e1w  = (const float*)d_in[5];
    const float* e1b  = (const float*)d_in[6];
    const float* e2w  = (const float*)d_in[7];
    const float* e2b  = (const float*)d_in[8];
    const float* wqx  = (const float*)d_in[9];
    const float* wkx  = (const float*)d_in[10];
    const float* wvx  = (const float*)d_in[11];
    const float* wox  = (const float*)d_in[12];
    const float* box_ = (const float*)d_in[13];
    const float* wqy  = (const float*)d_in[14];
    const float* wky  = (const float*)d_in[15];
    const float* wvy  = (const float*)d_in[16];
    const float* woy  = (const float*)d_in[17];
    const float* boy  = (const float*)d_in[18];
    const float* wqt  = (const float*)d_in[19];
    const float* wkt  = (const float*)d_in[20];
    const float* wvt  = (const float*)d_in[21];
    const float* wot  = (const float*)d_in[22];
    const float* bot  = (const float*)d_in[23];
    const float* ng   = (const float*)d_in[24];
    const float* nb   = (const float*)d_in[25];
    const float* pjw  = (const float*)d_in[26];
    const float* pjb  = (const float*)d_in[27];

    bf16* A = (bf16*)d_ws;     // 4 MiB in workspace
    unsigned* A16 = (unsigned*)((char*)d_ws + (4 << 20));  // 4 MiB f16 shadow
    bf16* R = (bf16*)d_out;    // 4 MiB scratch inside the 8 MiB f32 output buf
                               // (fully overwritten by conv_out at the end)

    // MFMA conv stem: 1024 blocks x 4 rows (both halves)
    conv_in_kernel<<<2 * NIMG * (HH / 4), 256, 0, stream>>>(
        hid, ref, ciw, cib, emb, e1w, e1b, e2w, e2b, A, R);

    // Stage X: seq=(b,f,h), S=2W=128, token stride 16, TPT=2
    attn_kernel<128, 1, 8, false><<<BB * FF * HH, 256, 0, stream>>>(
        A, R, nullptr, 1, WW * CC, 0, CC, wqx, wkx, wvx, wox, box_, ng, nb);
    // Stage Y: seq=(b,f,w), S=2H=128, tok stride W*C; SEQPB=1 -> 2048 blocks
    attn_kernel<128, 1, 8, false><<<BB * FF * WW, 256, 0, stream>>>(
        A, R, nullptr, WW, IMGSZ, CC, WW * CC, wqy, wky, wvy, woy, boy, ng, nb);
    // Stage T: seq=(b,h,w), S=2F=32; writes f16 shadow A16 only
    attn_kernel<32, 4, 8, true><<<(BB * HH * WW) / 4, 256, 0, stream>>>(
        A, R, A16, HH * WW, FF * IMGSZ, CC, IMGSZ, wqt, wkt, wvt, wot, bot, ng, nb);

    // MFMA conv_out: 1024 blocks x 2 rows
    conv_out_kernel<<<NIMG * (HH / 2), 256, 0, stream>>>(
        A16, hid, pjw, pjb, (float*)d_out);
}